// Round 1
// baseline (174.642 us; speedup 1.0000x reference)
//
#include <hip/hip_runtime.h>

// Problem constants (from reference setup_inputs): B=64, H=W=512, fp32.
#define BB 64
#define HH 512
#define WW 512
#define W4 (WW / 4)   // 128 float4s per row

// One thread per aligned float4 of output.
// t = b*(H*W4) + i*W4 + j4 ; consecutive threads -> consecutive j4 (coalesced).
__global__ __launch_bounds__(256) void jacobi_step_kernel(
    const float* __restrict__ x,
    const float* __restrict__ f,
    const float* __restrict__ k,
    float* __restrict__ out)
{
    const int t  = blockIdx.x * 256 + threadIdx.x;
    const int j4 = t & (W4 - 1);          // W4 = 128 = 2^7
    const int i  = (t >> 7) & (HH - 1);   // H  = 512 = 2^9
    const int b  = t >> 16;               // 7 + 9
    if (b >= BB) return;

    const float*  xb  = x + (size_t)b * HH * WW;
    const float4* xb4 = (const float4*)xb;
    const float*  kb  = k + b * 9;        // wave-uniform: L1-broadcast

    const float k00 = kb[0], k01 = kb[1], k02 = kb[2];
    const float k10 = kb[3], k11 = kb[4], k12 = kb[5];
    const float k20 = kb[6], k21 = kb[7], k22 = kb[8];

    const int j0 = j4 << 2;
    const bool has_l = (j0 > 0);
    const bool has_r = (j0 + 4 < WW);

    // center row (always valid)
    const float4 vc = xb4[i * W4 + j4];
    const float  lc = has_l ? xb[i * WW + j0 - 1] : 0.f;
    const float  rc = has_r ? xb[i * WW + j0 + 4] : 0.f;

    // row i-1 (zero-padded at i==0)
    float4 vm = make_float4(0.f, 0.f, 0.f, 0.f);
    float  lm = 0.f, rm = 0.f;
    if (i > 0) {
        vm = xb4[(i - 1) * W4 + j4];
        lm = has_l ? xb[(i - 1) * WW + j0 - 1] : 0.f;
        rm = has_r ? xb[(i - 1) * WW + j0 + 4] : 0.f;
    }

    // row i+1 (zero-padded at i==H-1)
    float4 vp = make_float4(0.f, 0.f, 0.f, 0.f);
    float  lp = 0.f, rp = 0.f;
    if (i < HH - 1) {
        vp = xb4[(i + 1) * W4 + j4];
        lp = has_l ? xb[(i + 1) * WW + j0 - 1] : 0.f;
        rp = has_r ? xb[(i + 1) * WW + j0 + 4] : 0.f;
    }

    // Cross-correlation: k[r][c] multiplies x[i+r-1][j+c-1]
    float4 acc;
    acc.x = k00 * lm   + k01 * vm.x + k02 * vm.y
          + k10 * lc   + k11 * vc.x + k12 * vc.y
          + k20 * lp   + k21 * vp.x + k22 * vp.y;
    acc.y = k00 * vm.x + k01 * vm.y + k02 * vm.z
          + k10 * vc.x + k11 * vc.y + k12 * vc.z
          + k20 * vp.x + k21 * vp.y + k22 * vp.z;
    acc.z = k00 * vm.y + k01 * vm.z + k02 * vm.w
          + k10 * vc.y + k11 * vc.z + k12 * vc.w
          + k20 * vp.y + k21 * vp.z + k22 * vp.w;
    acc.w = k00 * vm.z + k01 * vm.w + k02 * rm
          + k10 * vc.z + k11 * vc.w + k12 * rc
          + k20 * vp.z + k21 * vp.w + k22 * rp;

    const size_t idx4 = (size_t)b * HH * W4 + (size_t)i * W4 + j4;
    const float4 fv = ((const float4*)f)[idx4];

    const float inv6 = 1.f / 6.f;
    float4 o;
    o.x = vc.x + (fv.x - acc.x) * inv6;
    o.y = vc.y + (fv.y - acc.y) * inv6;
    o.z = vc.z + (fv.z - acc.z) * inv6;
    o.w = vc.w + (fv.w - acc.w) * inv6;

    ((float4*)out)[idx4] = o;
}

extern "C" void kernel_launch(void* const* d_in, const int* in_sizes, int n_in,
                              void* d_out, int out_size, void* d_ws, size_t ws_size,
                              hipStream_t stream) {
    const float* x = (const float*)d_in[0];
    const float* f = (const float*)d_in[1];
    const float* k = (const float*)d_in[2];
    float* out = (float*)d_out;

    const int total_quads = BB * HH * W4;          // 4,194,304
    const int blocks = (total_quads + 255) / 256;  // 16,384
    jacobi_step_kernel<<<blocks, 256, 0, stream>>>(x, f, k, out);
}